// Round 8
// baseline (361.890 us; speedup 1.0000x reference)
//
#include <hip/hip_runtime.h>

#define N_NODES   50000
#define N_EDGES   800000
#define DIM       96
#define N_GRAPHS  128
#define OUT_DIM   10
#define NPAD      50048        // 782 * 64 rows (gemm grid coverage)
#define CAP       64           // per-node bucket capacity (Poisson(16) tail ~1e-20)
#define NBINS     391          // coarse bins of 128 nodes
#define BINCAP    4096         // edges per coarse bin (Poisson(2048))
#define P1_BLOCKS 256
#define EPB       (N_EDGES / P1_BLOCKS)   // 3125
#define LPAD      104          // LDS agg row stride (bank-spread for b128 reads)
#define NDB       65           // degree buckets 0..64
#define PBCAP     8192         // per-deg-bucket capacity (peak bucket ~5k, 48 sigma margin)

#define CAST_NB   ((N_NODES * 12 + 255) / 256)        // 2344
#define CONV_NB   ((3 * DIM * 2 * DIM + 255) / 256)   // 216
#define ZERO_CNT  ((NBINS + NDB) * 16)
#define ZERO_NB   ((ZERO_CNT + 255) / 256)

typedef __attribute__((ext_vector_type(8))) short          short8;
typedef __attribute__((ext_vector_type(8))) unsigned short u16x8;
typedef __attribute__((ext_vector_type(4))) float          f32x4;

__device__ __forceinline__ float b2f(unsigned short u) {
    union { unsigned int i; float f; } v; v.i = ((unsigned int)u) << 16; return v.f;
}
__device__ __forceinline__ unsigned short f2b(float f) {   // round-to-nearest-even
    union { float f; unsigned int i; } v; v.f = f;
    unsigned int u = v.i;
    return (unsigned short)((u + 0x7fffu + ((u >> 16) & 1u)) >> 16);
}

// ---------------------------------------------------------------------------
// prep: grid-partitioned fusion of {cast x -> bf16, build Bt, zero cursors}.
// ---------------------------------------------------------------------------
__global__ __launch_bounds__(256) void prep(const float* __restrict__ x,
                                            const float* __restrict__ W1,
                                            const float* __restrict__ W2,
                                            unsigned short* __restrict__ harr,
                                            unsigned short* __restrict__ Bt,
                                            int* __restrict__ gcur)
{
    const int b = blockIdx.x;
    const int t = threadIdx.x;
    if (b < CAST_NB) {
        const int tid = b * 256 + t;                  // one per 8 cols
        if (tid >= N_NODES * 12) return;
        const int node = tid / 12;
        const int c    = (tid - node * 12) * 8;
        const float4 v0 = *(const float4*)(x + (size_t)node * DIM + c);
        const float4 v1 = *(const float4*)(x + (size_t)node * DIM + c + 4);
        u16x8 o;
        o[0] = f2b(v0.x); o[1] = f2b(v0.y); o[2] = f2b(v0.z); o[3] = f2b(v0.w);
        o[4] = f2b(v1.x); o[5] = f2b(v1.y); o[6] = f2b(v1.z); o[7] = f2b(v1.w);
        *(u16x8*)(harr + (size_t)node * DIM + c) = o;
    } else if (b < CAST_NB + CONV_NB) {
        const int idx = (b - CAST_NB) * 256 + t;      // Bt[l][n][k], k-major
        if (idx >= 3 * DIM * 2 * DIM) return;
        const int l   = idx / (DIM * 2 * DIM);
        const int rem = idx - l * (DIM * 2 * DIM);
        const int n   = rem / (2 * DIM);
        const int k   = rem - n * (2 * DIM);
        const float v = (k < DIM) ? W1[(size_t)l * DIM * DIM + k * DIM + n]
                                  : W2[(size_t)l * DIM * DIM + (k - DIM) * DIM + n];
        Bt[idx] = f2b(v);
    } else {
        const int i = (b - CAST_NB - CONV_NB) * 256 + t;
        if (i < ZERO_CNT) gcur[i] = 0;                // gcur + bcnt (contiguous)
    }
}

// ---------------------------------------------------------------------------
// Two-pass binned bucket build (round-5 evidence: returning device atomics cap
// at ~16G/s; this uses ~150k global atomics + LDS-local contention).
// Pass 1: coarse-bin edges by dst>>7, packing (dstLow<<16)|src.
// ---------------------------------------------------------------------------
__global__ __launch_bounds__(256) void pass1_bin(const int* __restrict__ src,
                                                 const int* __restrict__ dst,
                                                 int* __restrict__ gcur,
                                                 int* __restrict__ binned)
{
    __shared__ int hist[NBINS];
    __shared__ int base[NBINS];
    const int t  = threadIdx.x;
    const int e0 = blockIdx.x * EPB;

    for (int b = t; b < NBINS; b += 256) hist[b] = 0;
    __syncthreads();

    for (int e = e0 + t; e < e0 + EPB; e += 256)
        atomicAdd(&hist[dst[e] >> 7], 1);
    __syncthreads();

    for (int b = t; b < NBINS; b += 256) {
        const int c = hist[b];
        base[b] = (c > 0) ? atomicAdd(&gcur[b << 4], c) : 0;
        hist[b] = 0;                       // reuse as local cursor
    }
    __syncthreads();

    for (int e = e0 + t; e < e0 + EPB; e += 256) {
        const int d   = dst[e];
        const int bin = d >> 7;
        const int pos = base[bin] + atomicAdd(&hist[bin], 1);
        if (pos < BINCAP)
            binned[bin * BINCAP + pos] = ((d & 127) << 16) | src[e];
    }
}

// Pass 2: one block per bin (128 nodes); LDS cursors claim per-node slots.
// Tail fused: degree counting-sort scatter (node -> pbin[deg bucket]).
__global__ __launch_bounds__(256) void pass2_scatter(const int* __restrict__ gcur,
                                                     const int* __restrict__ binned,
                                                     int* __restrict__ csrc,
                                                     int* __restrict__ deg,
                                                     int* __restrict__ bcnt,
                                                     int* __restrict__ pbin)
{
    __shared__ int ncnt[128];
    const int bin = blockIdx.x;
    const int t   = threadIdx.x;
    const int n0  = bin << 7;
    const int cnt = min(gcur[bin << 4], BINCAP);

    if (t < 128) ncnt[t] = 0;
    __syncthreads();

    const int* __restrict__ bb = binned + bin * BINCAP;
    for (int i = t; i < cnt; i += 256) {
        const int v    = bb[i];
        const int dlow = v >> 16;
        const int s    = v & 0xffff;
        const int pos  = atomicAdd(&ncnt[dlow], 1);
        if (pos < CAP) csrc[(size_t)(n0 + dlow) * CAP + pos] = s;
    }
    __syncthreads();

    if (t < 128 && n0 + t < N_NODES) {
        const int n = n0 + t;
        const int d = min(ncnt[t], CAP);
        deg[n] = d;
        const int pos = atomicAdd(&bcnt[d << 4], 1);
        if (pos < PBCAP) pbin[d * PBCAP + pos] = n;
    }
}

// Tiny: exclusive prefix of the 65 degree-bucket counts -> boff[66].
__global__ __launch_bounds__(128) void bucket_prefix(const int* __restrict__ bcnt,
                                                     int* __restrict__ boff)
{
    __shared__ int c[NDB];
    const int t = threadIdx.x;
    if (t < NDB) c[t] = min(bcnt[t << 4], PBCAP);
    __syncthreads();
    if (t == 0) {
        int acc = 0;
        for (int b = 0; b < NDB; b++) { boff[b] = acc; acc += c[b]; }
        boff[NDB] = acc;      // == N_NODES
    }
}

// ---------------------------------------------------------------------------
// Fused layer with DEGREE-SORTED tile mapping: tile row g -> node =
// pbin[bucket(g)] so each wave's 64 lanes have near-identical deg (kills the
// max-of-11-Poissons divergence, ~1.6x on gather trips).  Buffers stay
// node-indexed; per-tile nodeIds[] LDS table routes phase-2 reads/writes.
// Phase 2: mfma_f32_16x16x32_bf16, A-frag A[m=lane&15][k=quad*8+j], C/D
// col=lane&15,row=quad*4+reg (m89-verified).  LPAD=104 bank-spreads ds_read_b128.
// ---------------------------------------------------------------------------
__global__ __launch_bounds__(384) void gnn_layer(
    const unsigned short* __restrict__ harr, const int* __restrict__ deg,
    const int* __restrict__ csrc, const int* __restrict__ pbin,
    const int* __restrict__ boff, const unsigned short* __restrict__ Btl,
    unsigned short* __restrict__ hout)
{
    __shared__ unsigned short aggLds[64][LPAD];
    __shared__ int boffL[NDB + 1];
    __shared__ int nodeIds[64];
    const int t       = threadIdx.x;
    const int rowBase = blockIdx.x * 64;

    if (t < NDB + 1) boffL[t] = boff[t];
    __syncthreads();

    // ---- phase 1: gather (deg-uniform waves) ----
    {
        const int r   = t / 6;           // 0..63
        const int sub = t - r * 6;       // 0..5
        const int g   = rowBase + r;
        const int off = sub * 16;        // 16 bf16 = 32B per thread

        int node = -1;
        if (g < N_NODES) {
            int lo = 0, hi = NDB - 1;    // largest b with boffL[b] <= g
            while (lo < hi) { int mid = (lo + hi + 1) >> 1;
                              if (boffL[mid] <= g) lo = mid; else hi = mid - 1; }
            node = pbin[lo * PBCAP + (g - boffL[lo])];
        }
        if (sub == 0) nodeIds[r] = node;

        float a[16];
#pragma unroll
        for (int i = 0; i < 16; i++) a[i] = 0.f;

        if (node >= 0) {
            const int d = deg[node];
            const int* __restrict__ bkt = csrc + (size_t)node * CAP;
            const unsigned short* __restrict__ hb = harr + off;

            const int nfull = d & ~3;
            int c = 0;
            for (; c < nfull; c += 4) {
                const int4 s = *(const int4*)(bkt + c);
                const unsigned short* p0 = hb + (size_t)s.x * DIM;
                const unsigned short* p1 = hb + (size_t)s.y * DIM;
                const unsigned short* p2 = hb + (size_t)s.z * DIM;
                const unsigned short* p3 = hb + (size_t)s.w * DIM;
                const u16x8 va0 = *(const u16x8*)(p0), vb0 = *(const u16x8*)(p0 + 8);
                const u16x8 va1 = *(const u16x8*)(p1), vb1 = *(const u16x8*)(p1 + 8);
                const u16x8 va2 = *(const u16x8*)(p2), vb2 = *(const u16x8*)(p2 + 8);
                const u16x8 va3 = *(const u16x8*)(p3), vb3 = *(const u16x8*)(p3 + 8);
#pragma unroll
                for (int i = 0; i < 8; i++) {
                    a[i]     += b2f(va0[i]) + b2f(va1[i]) + b2f(va2[i]) + b2f(va3[i]);
                    a[i + 8] += b2f(vb0[i]) + b2f(vb1[i]) + b2f(vb2[i]) + b2f(vb3[i]);
                }
            }
            for (; c < d; c++) {
                const unsigned short* p0 = hb + (size_t)bkt[c] * DIM;
                const u16x8 va0 = *(const u16x8*)(p0), vb0 = *(const u16x8*)(p0 + 8);
#pragma unroll
                for (int i = 0; i < 8; i++) {
                    a[i]     += b2f(va0[i]);
                    a[i + 8] += b2f(vb0[i]);
                }
            }
        }

        u16x8 o0, o1;
#pragma unroll
        for (int i = 0; i < 8; i++) { o0[i] = f2b(a[i]); o1[i] = f2b(a[i + 8]); }
        *(u16x8*)(&aggLds[r][off])     = o0;
        *(u16x8*)(&aggLds[r][off + 8]) = o1;
    }
    __syncthreads();

    // ---- phase 2: MFMA ----
    const int lane = t & 63;
    const int w    = t >> 6;    // 0..5 col tile
    const int m    = lane & 15;
    const int q    = lane >> 4;

    short8 bfrag[6];
#pragma unroll
    for (int s = 0; s < 6; s++)
        bfrag[s] = *(const short8*)(Btl + (size_t)(w * 16 + m) * (2 * DIM) + s * 32 + q * 8);

#pragma unroll
    for (int r = 0; r < 4; r++) {
        f32x4 acc = {0.f, 0.f, 0.f, 0.f};
        const int nodeA = nodeIds[r * 16 + m];
        const unsigned short* ah = harr + (size_t)max(nodeA, 0) * DIM + q * 8;
#pragma unroll
        for (int s = 0; s < 3; s++) {
            const short8 af = *(const short8*)(ah + s * 32);
            acc = __builtin_amdgcn_mfma_f32_16x16x32_bf16(af, bfrag[s], acc, 0, 0, 0);
        }
#pragma unroll
        for (int s = 0; s < 3; s++) {
            const short8 af = *(const short8*)(&aggLds[r * 16 + m][s * 32 + q * 8]);
            acc = __builtin_amdgcn_mfma_f32_16x16x32_bf16(af, bfrag[s + 3], acc, 0, 0, 0);
        }
#pragma unroll
        for (int i = 0; i < 4; i++) {
            const int nodeC = nodeIds[r * 16 + q * 4 + i];
            if (nodeC >= 0)
                hout[(size_t)nodeC * DIM + w * 16 + m] = f2b(fmaxf(acc[i], 0.f));
        }
    }
}

// ---------------------------------------------------------------------------
// Fused pool + classifier (batch sorted -> contiguous ranges; h node-ordered).
// ---------------------------------------------------------------------------
__global__ __launch_bounds__(384) void pool_classify(
    const unsigned short* __restrict__ h, const int* __restrict__ batch,
    const float* __restrict__ cw1, const float* __restrict__ cb1,
    const float* __restrict__ cw2, const float* __restrict__ cb2,
    float* __restrict__ out)
{
    const int g = blockIdx.x;
    const int t = threadIdx.x;

    int lo = 0, hi = N_NODES;
    while (lo < hi) { int m = (lo + hi) >> 1; if (batch[m] < g) lo = m + 1; else hi = m; }
    const int start = lo;
    hi = N_NODES;
    while (lo < hi) { int m = (lo + hi) >> 1; if (batch[m] < g + 1) lo = m + 1; else hi = m; }
    const int end = lo;

    __shared__ float part[4][DIM];
    __shared__ float gr[DIM];
    __shared__ float hid[DIM];

    const int col = t % DIM;     // 0..95
    const int ty  = t / DIM;     // 0..3

    float s = 0.f;
    for (int n = start + ty; n < end; n += 4)
        s += b2f(h[(size_t)n * DIM + col]);
    part[ty][col] = s;
    __syncthreads();
    if (ty == 0)
        gr[col] = part[0][col] + part[1][col] + part[2][col] + part[3][col];
    __syncthreads();

    float hsum = 0.f;
    const int k0 = ty * (DIM / 4);
#pragma unroll 4
    for (int k = k0; k < k0 + DIM / 4; k++)
        hsum += gr[k] * cw1[k * DIM + col];
    part[ty][col] = hsum;
    __syncthreads();
    if (ty == 0)
        hid[col] = fmaxf(part[0][col] + part[1][col] + part[2][col] + part[3][col]
                         + cb1[col], 0.f);
    __syncthreads();

    if (t < OUT_DIM) {
        float o = cb2[t];
#pragma unroll 4
        for (int k = 0; k < DIM; k++) o += hid[k] * cw2[k * OUT_DIM + t];
        out[g * OUT_DIM + t] = o;
    }
}

// ---------------------------------------------------------------------------
extern "C" void kernel_launch(void* const* d_in, const int* in_sizes, int n_in,
                              void* d_out, int out_size, void* d_ws, size_t ws_size,
                              hipStream_t stream)
{
    const float* x     = (const float*)d_in[0];
    const int*   ei    = (const int*)  d_in[1];
    const int*   batch = (const int*)  d_in[2];
    const float* W1    = (const float*)d_in[3];
    const float* W2    = (const float*)d_in[4];
    const float* cw1   = (const float*)d_in[5];
    const float* cb1   = (const float*)d_in[6];
    const float* cw2   = (const float*)d_in[7];
    const float* cb2   = (const float*)d_in[8];
    float*       out   = (float*)d_out;

    const int* src = ei;             // edge_index[0]
    const int* dst = ei + N_EDGES;   // edge_index[1]

    // workspace layout (16B-aligned at each boundary)
    unsigned short* bufA = (unsigned short*)d_ws;          // [NPAD,96] bf16
    unsigned short* bufB = bufA + (size_t)NPAD * DIM;      // [NPAD,96] bf16
    unsigned short* Bt   = bufB + (size_t)NPAD * DIM;      // [3,96,192] bf16
    int*   gcur   = (int*)(Bt + 3 * DIM * 2 * DIM);        // [NBINS*16] line-padded
    int*   bcnt   = gcur + NBINS * 16;                     // [NDB*16] line-padded
    int*   binned = bcnt + NDB * 16;                       // [NBINS*BINCAP]
    int*   csrc   = binned + (size_t)NBINS * BINCAP;       // [N*CAP]
    int*   deg    = csrc + (size_t)N_NODES * CAP;          // [N]
    int*   pbin   = deg + N_NODES;                         // [NDB*PBCAP]
    int*   boff   = pbin + NDB * PBCAP;                    // [NDB+1]

    prep<<<CAST_NB + CONV_NB + ZERO_NB, 256, 0, stream>>>(x, W1, W2, bufA, Bt, gcur);
    pass1_bin<<<P1_BLOCKS, 256, 0, stream>>>(src, dst, gcur, binned);
    pass2_scatter<<<NBINS, 256, 0, stream>>>(gcur, binned, csrc, deg, bcnt, pbin);
    bucket_prefix<<<1, 128, 0, stream>>>(bcnt, boff);

    unsigned short* hin  = bufA;
    unsigned short* hout = bufB;
    for (int l = 0; l < 3; l++) {
        gnn_layer<<<NPAD / 64, 384, 0, stream>>>(hin, deg, csrc, pbin, boff,
                                                 Bt + (size_t)l * DIM * 2 * DIM, hout);
        unsigned short* tmp = hin; hin = hout; hout = tmp;
    }

    pool_classify<<<N_GRAPHS, 384, 0, stream>>>(hin, batch, cw1, cb1, cw2, cb2, out);
}

// Round 9
// 291.080 us; speedup vs baseline: 1.2433x; 1.2433x over previous
//
#include <hip/hip_runtime.h>

#define N_NODES   50000
#define N_EDGES   800000
#define DIM       96
#define N_GRAPHS  128
#define OUT_DIM   10
#define NPAD      50048        // 782 * 64 rows (gemm grid coverage)
#define NBINS     391          // coarse bins of 128 nodes
#define BINCAP    4096         // edges per coarse bin (Poisson(2048))
#define P1_BLOCKS 256
#define EPB       (N_EDGES / P1_BLOCKS)   // 3125
#define LPAD      104          // LDS agg row stride (bank-spread for b128 reads)
#define CAP_P     32           // per-node per-src-partition capacity (Poisson(5.3))
#define CAPR      (3 * CAP_P)  // bucket row stride = 96 ints
#define PB1       16667        // src partition bounds (3.2MB slices < 4MB XCD L2)
#define PB2       33334

#define CAST_NB   ((N_NODES * 12 + 255) / 256)        // 2344
#define CONV_NB   ((3 * DIM * 2 * DIM + 255) / 256)   // 216
#define ZERO_CNT  (NBINS * 16)
#define ZERO_NB   ((ZERO_CNT + 255) / 256)

typedef __attribute__((ext_vector_type(8))) short          short8;
typedef __attribute__((ext_vector_type(8))) unsigned short u16x8;
typedef __attribute__((ext_vector_type(4))) float          f32x4;

__device__ __forceinline__ float b2f(unsigned short u) {
    union { unsigned int i; float f; } v; v.i = ((unsigned int)u) << 16; return v.f;
}
__device__ __forceinline__ unsigned short f2b(float f) {   // round-to-nearest-even
    union { float f; unsigned int i; } v; v.f = f;
    unsigned int u = v.i;
    return (unsigned short)((u + 0x7fffu + ((u >> 16) & 1u)) >> 16);
}

// ---------------------------------------------------------------------------
// prep: grid-partitioned fusion of {cast x -> bf16, build Bt, zero cursors}.
// ---------------------------------------------------------------------------
__global__ __launch_bounds__(256) void prep(const float* __restrict__ x,
                                            const float* __restrict__ W1,
                                            const float* __restrict__ W2,
                                            unsigned short* __restrict__ harr,
                                            unsigned short* __restrict__ Bt,
                                            int* __restrict__ gcur)
{
    const int b = blockIdx.x;
    const int t = threadIdx.x;
    if (b < CAST_NB) {
        const int tid = b * 256 + t;                  // one per 8 cols
        if (tid >= N_NODES * 12) return;
        const int node = tid / 12;
        const int c    = (tid - node * 12) * 8;
        const float4 v0 = *(const float4*)(x + (size_t)node * DIM + c);
        const float4 v1 = *(const float4*)(x + (size_t)node * DIM + c + 4);
        u16x8 o;
        o[0] = f2b(v0.x); o[1] = f2b(v0.y); o[2] = f2b(v0.z); o[3] = f2b(v0.w);
        o[4] = f2b(v1.x); o[5] = f2b(v1.y); o[6] = f2b(v1.z); o[7] = f2b(v1.w);
        *(u16x8*)(harr + (size_t)node * DIM + c) = o;
    } else if (b < CAST_NB + CONV_NB) {
        const int idx = (b - CAST_NB) * 256 + t;      // Bt[l][n][k], k-major
        if (idx >= 3 * DIM * 2 * DIM) return;
        const int l   = idx / (DIM * 2 * DIM);
        const int rem = idx - l * (DIM * 2 * DIM);
        const int n   = rem / (2 * DIM);
        const int k   = rem - n * (2 * DIM);
        const float v = (k < DIM) ? W1[(size_t)l * DIM * DIM + k * DIM + n]
                                  : W2[(size_t)l * DIM * DIM + (k - DIM) * DIM + n];
        Bt[idx] = f2b(v);
    } else {
        const int i = (b - CAST_NB - CONV_NB) * 256 + t;
        if (i < ZERO_CNT) gcur[i] = 0;
    }
}

// ---------------------------------------------------------------------------
// Two-pass binned bucket build (round-5 evidence: returning device atomics cap
// at ~16G/s; round-8 evidence: same-address global atomics serialize at
// ~120ns each -> keep ALL per-node/per-bucket contention in LDS).
// Pass 1: coarse-bin edges by dst>>7, packing (dstLow<<16)|src.
// ---------------------------------------------------------------------------
__global__ __launch_bounds__(256) void pass1_bin(const int* __restrict__ src,
                                                 const int* __restrict__ dst,
                                                 int* __restrict__ gcur,
                                                 int* __restrict__ binned)
{
    __shared__ int hist[NBINS];
    __shared__ int base[NBINS];
    const int t  = threadIdx.x;
    const int e0 = blockIdx.x * EPB;

    for (int b = t; b < NBINS; b += 256) hist[b] = 0;
    __syncthreads();

    for (int e = e0 + t; e < e0 + EPB; e += 256)
        atomicAdd(&hist[dst[e] >> 7], 1);
    __syncthreads();

    for (int b = t; b < NBINS; b += 256) {
        const int c = hist[b];
        base[b] = (c > 0) ? atomicAdd(&gcur[b << 4], c) : 0;
        hist[b] = 0;                       // reuse as local cursor
    }
    __syncthreads();

    for (int e = e0 + t; e < e0 + EPB; e += 256) {
        const int d   = dst[e];
        const int bin = d >> 7;
        const int pos = base[bin] + atomicAdd(&hist[bin], 1);
        if (pos < BINCAP)
            binned[bin * BINCAP + pos] = ((d & 127) << 16) | src[e];
    }
}

// Pass 2: one block per bin (128 nodes); LDS sub-cursors (3 src partitions per
// node) claim slots -> csrc[node*CAPR + p*CAP_P + pos], sorted by partition.
// degp[node] packs the 3 counts (8 bits each).
__global__ __launch_bounds__(256) void pass2_scatter(const int* __restrict__ gcur,
                                                     const int* __restrict__ binned,
                                                     int* __restrict__ csrc,
                                                     int* __restrict__ degp)
{
    __shared__ int ncnt[128 * 3];
    const int bin = blockIdx.x;
    const int t   = threadIdx.x;
    const int n0  = bin << 7;
    const int cnt = min(gcur[bin << 4], BINCAP);

    if (t < 128) { ncnt[t * 3] = 0; ncnt[t * 3 + 1] = 0; ncnt[t * 3 + 2] = 0; }
    __syncthreads();

    const int* __restrict__ bb = binned + bin * BINCAP;
    for (int i = t; i < cnt; i += 256) {
        const int v    = bb[i];
        const int dlow = v >> 16;
        const int s    = v & 0xffff;    // NOTE: src fits 16 bits (N_NODES<65536)
        const int p    = (s >= PB1) + (s >= PB2);
        const int pos  = atomicAdd(&ncnt[dlow * 3 + p], 1);
        if (pos < CAP_P)
            csrc[(size_t)(n0 + dlow) * CAPR + p * CAP_P + pos] = s;
    }
    __syncthreads();

    if (t < 128 && n0 + t < N_NODES) {
        const int d0 = min(ncnt[t * 3],     CAP_P);
        const int d1 = min(ncnt[t * 3 + 1], CAP_P);
        const int d2 = min(ncnt[t * 3 + 2], CAP_P);
        degp[n0 + t] = d0 | (d1 << 8) | (d2 << 16);
    }
}

// ---------------------------------------------------------------------------
// Fused layer: phase 1 gathers neighbor sums in 3 SRC-PARTITION passes (each
// pass touches a 3.2MB slice of harr -> XCD-L2 resident; round-8 falsified the
// divergence theory, pointing at L3 random-row service as the wall) into a
// padded LDS tile; phase 2 MFMAs Hout = relu([h | agg] @ B[192,96]).
// Phase 2: mfma_f32_16x16x32_bf16, A-frag A[m=lane&15][k=quad*8+j], C/D
// col=lane&15,row=quad*4+reg (m89-verified).  LPAD=104 bank-spreads ds_read_b128.
// ---------------------------------------------------------------------------
__global__ __launch_bounds__(384) void gnn_layer(
    const unsigned short* __restrict__ harr, const int* __restrict__ degp,
    const int* __restrict__ csrc, const unsigned short* __restrict__ Btl,
    unsigned short* __restrict__ hout)
{
    __shared__ unsigned short aggLds[64][LPAD];
    const int t       = threadIdx.x;
    const int rowBase = blockIdx.x * 64;

    // ---- phase 1: gather, 3 src-partition passes ----
    {
        const int r    = t / 6;          // 0..63
        const int sub  = t - r * 6;      // 0..5
        const int node = rowBase + r;
        const int off  = sub * 16;       // 16 bf16 = 32B per thread

        float a[16];
#pragma unroll
        for (int i = 0; i < 16; i++) a[i] = 0.f;

        if (node < N_NODES) {
            const int dpack = degp[node];
            const unsigned short* __restrict__ hb = harr + off;

#pragma unroll
            for (int p = 0; p < 3; p++) {
                const int d = (dpack >> (8 * p)) & 255;
                const int* __restrict__ bkt = csrc + (size_t)node * CAPR + p * CAP_P;

                const int nfull = d & ~3;
                int c = 0;
                for (; c < nfull; c += 4) {
                    const int4 s = *(const int4*)(bkt + c);
                    const unsigned short* p0 = hb + (size_t)s.x * DIM;
                    const unsigned short* p1 = hb + (size_t)s.y * DIM;
                    const unsigned short* p2 = hb + (size_t)s.z * DIM;
                    const unsigned short* p3 = hb + (size_t)s.w * DIM;
                    const u16x8 va0 = *(const u16x8*)(p0), vb0 = *(const u16x8*)(p0 + 8);
                    const u16x8 va1 = *(const u16x8*)(p1), vb1 = *(const u16x8*)(p1 + 8);
                    const u16x8 va2 = *(const u16x8*)(p2), vb2 = *(const u16x8*)(p2 + 8);
                    const u16x8 va3 = *(const u16x8*)(p3), vb3 = *(const u16x8*)(p3 + 8);
#pragma unroll
                    for (int i = 0; i < 8; i++) {
                        a[i]     += b2f(va0[i]) + b2f(va1[i]) + b2f(va2[i]) + b2f(va3[i]);
                        a[i + 8] += b2f(vb0[i]) + b2f(vb1[i]) + b2f(vb2[i]) + b2f(vb3[i]);
                    }
                }
                for (; c < d; c++) {
                    const unsigned short* p0 = hb + (size_t)bkt[c] * DIM;
                    const u16x8 va0 = *(const u16x8*)(p0), vb0 = *(const u16x8*)(p0 + 8);
#pragma unroll
                    for (int i = 0; i < 8; i++) {
                        a[i]     += b2f(va0[i]);
                        a[i + 8] += b2f(vb0[i]);
                    }
                }
            }
        }

        u16x8 o0, o1;
#pragma unroll
        for (int i = 0; i < 8; i++) { o0[i] = f2b(a[i]); o1[i] = f2b(a[i + 8]); }
        *(u16x8*)(&aggLds[r][off])     = o0;
        *(u16x8*)(&aggLds[r][off + 8]) = o1;
    }
    __syncthreads();

    // ---- phase 2: MFMA ----
    const int lane = t & 63;
    const int w    = t >> 6;    // 0..5 col tile
    const int m    = lane & 15;
    const int q    = lane >> 4;

    short8 bfrag[6];
#pragma unroll
    for (int s = 0; s < 6; s++)
        bfrag[s] = *(const short8*)(Btl + (size_t)(w * 16 + m) * (2 * DIM) + s * 32 + q * 8);

#pragma unroll
    for (int r = 0; r < 4; r++) {
        const int rb = rowBase + r * 16;
        f32x4 acc = {0.f, 0.f, 0.f, 0.f};
        const unsigned short* ah = harr + (size_t)(rb + m) * DIM + q * 8;
#pragma unroll
        for (int s = 0; s < 3; s++) {
            const short8 af = *(const short8*)(ah + s * 32);
            acc = __builtin_amdgcn_mfma_f32_16x16x32_bf16(af, bfrag[s], acc, 0, 0, 0);
        }
#pragma unroll
        for (int s = 0; s < 3; s++) {
            const short8 af = *(const short8*)(&aggLds[r * 16 + m][s * 32 + q * 8]);
            acc = __builtin_amdgcn_mfma_f32_16x16x32_bf16(af, bfrag[s + 3], acc, 0, 0, 0);
        }
#pragma unroll
        for (int i = 0; i < 4; i++) {
            const int grow = rb + q * 4 + i;
            if (grow < N_NODES)
                hout[(size_t)grow * DIM + w * 16 + m] = f2b(fmaxf(acc[i], 0.f));
        }
    }
}

// ---------------------------------------------------------------------------
// Fused pool + classifier (batch sorted -> contiguous ranges).
// ---------------------------------------------------------------------------
__global__ __launch_bounds__(384) void pool_classify(
    const unsigned short* __restrict__ h, const int* __restrict__ batch,
    const float* __restrict__ cw1, const float* __restrict__ cb1,
    const float* __restrict__ cw2, const float* __restrict__ cb2,
    float* __restrict__ out)
{
    const int g = blockIdx.x;
    const int t = threadIdx.x;

    int lo = 0, hi = N_NODES;
    while (lo < hi) { int m = (lo + hi) >> 1; if (batch[m] < g) lo = m + 1; else hi = m; }
    const int start = lo;
    hi = N_NODES;
    while (lo < hi) { int m = (lo + hi) >> 1; if (batch[m] < g + 1) lo = m + 1; else hi = m; }
    const int end = lo;

    __shared__ float part[4][DIM];
    __shared__ float gr[DIM];
    __shared__ float hid[DIM];

    const int col = t % DIM;     // 0..95
    const int ty  = t / DIM;     // 0..3

    float s = 0.f;
    for (int n = start + ty; n < end; n += 4)
        s += b2f(h[(size_t)n * DIM + col]);
    part[ty][col] = s;
    __syncthreads();
    if (ty == 0)
        gr[col] = part[0][col] + part[1][col] + part[2][col] + part[3][col];
    __syncthreads();

    float hsum = 0.f;
    const int k0 = ty * (DIM / 4);
#pragma unroll 4
    for (int k = k0; k < k0 + DIM / 4; k++)
        hsum += gr[k] * cw1[k * DIM + col];
    part[ty][col] = hsum;
    __syncthreads();
    if (ty == 0)
        hid[col] = fmaxf(part[0][col] + part[1][col] + part[2][col] + part[3][col]
                         + cb1[col], 0.f);
    __syncthreads();

    if (t < OUT_DIM) {
        float o = cb2[t];
#pragma unroll 4
        for (int k = 0; k < DIM; k++) o += hid[k] * cw2[k * OUT_DIM + t];
        out[g * OUT_DIM + t] = o;
    }
}

// ---------------------------------------------------------------------------
extern "C" void kernel_launch(void* const* d_in, const int* in_sizes, int n_in,
                              void* d_out, int out_size, void* d_ws, size_t ws_size,
                              hipStream_t stream)
{
    const float* x     = (const float*)d_in[0];
    const int*   ei    = (const int*)  d_in[1];
    const int*   batch = (const int*)  d_in[2];
    const float* W1    = (const float*)d_in[3];
    const float* W2    = (const float*)d_in[4];
    const float* cw1   = (const float*)d_in[5];
    const float* cb1   = (const float*)d_in[6];
    const float* cw2   = (const float*)d_in[7];
    const float* cb2   = (const float*)d_in[8];
    float*       out   = (float*)d_out;

    const int* src = ei;             // edge_index[0]
    const int* dst = ei + N_EDGES;   // edge_index[1]

    // workspace layout (16B-aligned at each boundary)
    unsigned short* bufA = (unsigned short*)d_ws;          // [NPAD,96] bf16
    unsigned short* bufB = bufA + (size_t)NPAD * DIM;      // [NPAD,96] bf16
    unsigned short* Bt   = bufB + (size_t)NPAD * DIM;      // [3,96,192] bf16
    int*   gcur   = (int*)(Bt + 3 * DIM * 2 * DIM);        // [NBINS*16] line-padded
    int*   binned = gcur + NBINS * 16;                     // [NBINS*BINCAP]
    int*   csrc   = binned + (size_t)NBINS * BINCAP;       // [N*CAPR]
    int*   degp   = csrc + (size_t)N_NODES * CAPR;         // [N] packed 3x8-bit

    prep<<<CAST_NB + CONV_NB + ZERO_NB, 256, 0, stream>>>(x, W1, W2, bufA, Bt, gcur);
    pass1_bin<<<P1_BLOCKS, 256, 0, stream>>>(src, dst, gcur, binned);
    pass2_scatter<<<NBINS, 256, 0, stream>>>(gcur, binned, csrc, degp);

    unsigned short* hin  = bufA;
    unsigned short* hout = bufB;
    for (int l = 0; l < 3; l++) {
        gnn_layer<<<NPAD / 64, 384, 0, stream>>>(hin, degp, csrc,
                                                 Bt + (size_t)l * DIM * 2 * DIM, hout);
        unsigned short* tmp = hin; hin = hout; hout = tmp;
    }

    pool_classify<<<N_GRAPHS, 384, 0, stream>>>(hin, batch, cw1, cb1, cw2, cb2, out);
}

// Round 10
// 275.888 us; speedup vs baseline: 1.3117x; 1.0551x over previous
//
#include <hip/hip_runtime.h>

#define N_NODES   50000
#define N_EDGES   800000
#define DIM       96
#define N_GRAPHS  128
#define OUT_DIM   10
#define NPAD      50048        // 782 * 64 rows (gemm grid coverage)
#define NBINS     391          // coarse bins of 128 nodes
#define P1_BLOCKS 128
#define EPB       (N_EDGES / P1_BLOCKS)   // 6250
#define SLICECAP  48           // per (bin,block) slice capacity: Poisson(16), P(>=48)~1e-10
#define CAP       64           // per-node bucket capacity (Poisson(16) tail ~1e-20)
#define LPAD      104          // LDS agg row stride (bank-spread for b128 reads)

#define CAST_NB   ((N_NODES * 12 + 255) / 256)        // 2344
#define CONV_NB   ((3 * DIM * 2 * DIM + 255) / 256)   // 216

typedef __attribute__((ext_vector_type(8))) short          short8;
typedef __attribute__((ext_vector_type(8))) unsigned short u16x8;
typedef __attribute__((ext_vector_type(4))) float          f32x4;

__device__ __forceinline__ float b2f(unsigned short u) {
    union { unsigned int i; float f; } v; v.i = ((unsigned int)u) << 16; return v.f;
}
__device__ __forceinline__ unsigned short f2b(float f) {   // round-to-nearest-even
    union { float f; unsigned int i; } v; v.f = f;
    unsigned int u = v.i;
    return (unsigned short)((u + 0x7fffu + ((u >> 16) & 1u)) >> 16);
}

// ---------------------------------------------------------------------------
// prep: grid-partitioned fusion of {cast x -> bf16, build Bt}.
// ---------------------------------------------------------------------------
__global__ __launch_bounds__(256) void prep(const float* __restrict__ x,
                                            const float* __restrict__ W1,
                                            const float* __restrict__ W2,
                                            unsigned short* __restrict__ harr,
                                            unsigned short* __restrict__ Bt)
{
    const int b = blockIdx.x;
    const int t = threadIdx.x;
    if (b < CAST_NB) {
        const int tid = b * 256 + t;                  // one per 8 cols
        if (tid >= N_NODES * 12) return;
        const int node = tid / 12;
        const int c    = (tid - node * 12) * 8;
        const float4 v0 = *(const float4*)(x + (size_t)node * DIM + c);
        const float4 v1 = *(const float4*)(x + (size_t)node * DIM + c + 4);
        u16x8 o;
        o[0] = f2b(v0.x); o[1] = f2b(v0.y); o[2] = f2b(v0.z); o[3] = f2b(v0.w);
        o[4] = f2b(v1.x); o[5] = f2b(v1.y); o[6] = f2b(v1.z); o[7] = f2b(v1.w);
        *(u16x8*)(harr + (size_t)node * DIM + c) = o;
    } else {
        const int idx = (b - CAST_NB) * 256 + t;      // Bt[l][n][k], k-major
        if (idx >= 3 * DIM * 2 * DIM) return;
        const int l   = idx / (DIM * 2 * DIM);
        const int rem = idx - l * (DIM * 2 * DIM);
        const int n   = rem / (2 * DIM);
        const int k   = rem - n * (2 * DIM);
        const float v = (k < DIM) ? W1[(size_t)l * DIM * DIM + k * DIM + n]
                                  : W2[(size_t)l * DIM * DIM + (k - DIM) * DIM + n];
        Bt[idx] = f2b(v);
    }
}

// ---------------------------------------------------------------------------
// ZERO-global-atomic bucket build (round-8/9 evidence: same-address returning
// global atomics serialize at ~120ns; 256 blocks x 391 lines cost ~30-40us).
// Pass 1: each block owns private slices binned[bin][blk][SLICECAP]; LDS
// cursors only, plain global writes; cnt[bin][blk] written for all bins.
// ---------------------------------------------------------------------------
__global__ __launch_bounds__(256) void pass1_bin(const int* __restrict__ src,
                                                 const int* __restrict__ dst,
                                                 int* __restrict__ binned,
                                                 int* __restrict__ cnt)
{
    __shared__ int cur[NBINS];
    const int t   = threadIdx.x;
    const int blk = blockIdx.x;
    const int e0  = blk * EPB;

    for (int b = t; b < NBINS; b += 256) cur[b] = 0;
    __syncthreads();

    for (int e = e0 + t; e < e0 + EPB; e += 256) {
        const int d   = dst[e];
        const int bin = d >> 7;
        const int pos = atomicAdd(&cur[bin], 1);
        if (pos < SLICECAP)
            binned[((size_t)bin * P1_BLOCKS + blk) * SLICECAP + pos]
                = ((d & 127) << 16) | src[e];
    }
    __syncthreads();

    for (int b = t; b < NBINS; b += 256)
        cnt[b * P1_BLOCKS + blk] = min(cur[b], SLICECAP);
}

// Pass 2: one block per bin (128 nodes).  LDS scan of the 128 slice counts ->
// offsets; walk all bin edges (LDS binary search for slice); LDS per-node
// cursors claim csrc slots.  No global atomics.
__global__ __launch_bounds__(256) void pass2_scatter(const int* __restrict__ cnt,
                                                     const int* __restrict__ binned,
                                                     int* __restrict__ csrc,
                                                     int* __restrict__ deg)
{
    __shared__ int buf[2][P1_BLOCKS];
    __shared__ int soff[P1_BLOCKS + 1];
    __shared__ int ncnt[128];
    const int bin = blockIdx.x;
    const int t   = threadIdx.x;
    const int n0  = bin << 7;

    if (t < P1_BLOCKS) { buf[0][t] = cnt[bin * P1_BLOCKS + t]; ncnt[t] = 0; }
    __syncthreads();

    int c = 0;
#pragma unroll
    for (int off = 1; off < P1_BLOCKS; off <<= 1) {   // inclusive scan
        if (t < P1_BLOCKS) {
            int x = buf[c][t];
            if (t >= off) x += buf[c][t - off];
            buf[c ^ 1][t] = x;
        }
        __syncthreads();
        c ^= 1;
    }
    if (t < P1_BLOCKS) { soff[t + 1] = buf[c][t]; if (t == 0) soff[0] = 0; }
    __syncthreads();

    const int Eb = soff[P1_BLOCKS];
    for (int i = t; i < Eb; i += 256) {
        int lo = 0, hi = P1_BLOCKS - 1;               // largest s: soff[s] <= i
        while (lo < hi) { int mid = (lo + hi + 1) >> 1;
                          if (soff[mid] <= i) lo = mid; else hi = mid - 1; }
        const int v    = binned[((size_t)bin * P1_BLOCKS + lo) * SLICECAP + (i - soff[lo])];
        const int dlow = v >> 16;
        const int s    = v & 0xffff;                  // src fits 16 bits (N<65536)
        const int pos  = atomicAdd(&ncnt[dlow], 1);   // LDS atomic
        if (pos < CAP) csrc[(size_t)(n0 + dlow) * CAP + pos] = s;
    }
    __syncthreads();

    if (t < 128 && n0 + t < N_NODES) deg[n0 + t] = min(ncnt[t], CAP);
}

// ---------------------------------------------------------------------------
// Fused layer (round-7 single-bucket gather — round-9 falsified both the
// divergence and the L2-partition theories; ~44us is the ILP-structured rate).
// Phase 1: 6 threads/row x 32B, unroll 4 -> 8 loads in flight/thread.
// Phase 2: mfma_f32_16x16x32_bf16, A-frag A[m=lane&15][k=quad*8+j], C/D
// col=lane&15,row=quad*4+reg (m89-verified).  LPAD=104 bank-spreads ds_read_b128.
// bfrag loads hoisted above the gather so B-fetch overlaps gather latency.
// ---------------------------------------------------------------------------
__global__ __launch_bounds__(384) void gnn_layer(
    const unsigned short* __restrict__ harr, const int* __restrict__ deg,
    const int* __restrict__ csrc, const unsigned short* __restrict__ Btl,
    unsigned short* __restrict__ hout)
{
    __shared__ unsigned short aggLds[64][LPAD];
    const int t       = threadIdx.x;
    const int rowBase = blockIdx.x * 64;

    // hoisted B fragments (overlap with gather)
    const int lane = t & 63;
    const int w    = t >> 6;    // 0..5 col tile
    const int m    = lane & 15;
    const int q    = lane >> 4;
    short8 bfrag[6];
#pragma unroll
    for (int s = 0; s < 6; s++)
        bfrag[s] = *(const short8*)(Btl + (size_t)(w * 16 + m) * (2 * DIM) + s * 32 + q * 8);

    // ---- phase 1: gather ----
    {
        const int r    = t / 6;          // 0..63
        const int sub  = t - r * 6;      // 0..5
        const int node = rowBase + r;
        const int off  = sub * 16;       // 16 bf16 = 32B per thread

        float a[16];
#pragma unroll
        for (int i = 0; i < 16; i++) a[i] = 0.f;

        if (node < N_NODES) {
            const int d = deg[node];
            const int* __restrict__ bkt = csrc + (size_t)node * CAP;
            const unsigned short* __restrict__ hb = harr + off;

            const int nfull = d & ~3;
            int c = 0;
            for (; c < nfull; c += 4) {
                const int4 s = *(const int4*)(bkt + c);
                const unsigned short* p0 = hb + (size_t)s.x * DIM;
                const unsigned short* p1 = hb + (size_t)s.y * DIM;
                const unsigned short* p2 = hb + (size_t)s.z * DIM;
                const unsigned short* p3 = hb + (size_t)s.w * DIM;
                const u16x8 va0 = *(const u16x8*)(p0), vb0 = *(const u16x8*)(p0 + 8);
                const u16x8 va1 = *(const u16x8*)(p1), vb1 = *(const u16x8*)(p1 + 8);
                const u16x8 va2 = *(const u16x8*)(p2), vb2 = *(const u16x8*)(p2 + 8);
                const u16x8 va3 = *(const u16x8*)(p3), vb3 = *(const u16x8*)(p3 + 8);
#pragma unroll
                for (int i = 0; i < 8; i++) {
                    a[i]     += b2f(va0[i]) + b2f(va1[i]) + b2f(va2[i]) + b2f(va3[i]);
                    a[i + 8] += b2f(vb0[i]) + b2f(vb1[i]) + b2f(vb2[i]) + b2f(vb3[i]);
                }
            }
            for (; c < d; c++) {
                const unsigned short* p0 = hb + (size_t)bkt[c] * DIM;
                const u16x8 va0 = *(const u16x8*)(p0), vb0 = *(const u16x8*)(p0 + 8);
#pragma unroll
                for (int i = 0; i < 8; i++) {
                    a[i]     += b2f(va0[i]);
                    a[i + 8] += b2f(vb0[i]);
                }
            }
        }

        u16x8 o0, o1;
#pragma unroll
        for (int i = 0; i < 8; i++) { o0[i] = f2b(a[i]); o1[i] = f2b(a[i + 8]); }
        *(u16x8*)(&aggLds[r][off])     = o0;
        *(u16x8*)(&aggLds[r][off + 8]) = o1;
    }
    __syncthreads();

    // ---- phase 2: MFMA ----
#pragma unroll
    for (int r = 0; r < 4; r++) {
        const int rb = rowBase + r * 16;
        f32x4 acc = {0.f, 0.f, 0.f, 0.f};
        const unsigned short* ah = harr + (size_t)(rb + m) * DIM + q * 8;
#pragma unroll
        for (int s = 0; s < 3; s++) {
            const short8 af = *(const short8*)(ah + s * 32);
            acc = __builtin_amdgcn_mfma_f32_16x16x32_bf16(af, bfrag[s], acc, 0, 0, 0);
        }
#pragma unroll
        for (int s = 0; s < 3; s++) {
            const short8 af = *(const short8*)(&aggLds[r * 16 + m][s * 32 + q * 8]);
            acc = __builtin_amdgcn_mfma_f32_16x16x32_bf16(af, bfrag[s + 3], acc, 0, 0, 0);
        }
#pragma unroll
        for (int i = 0; i < 4; i++) {
            const int grow = rb + q * 4 + i;
            if (grow < N_NODES)
                hout[(size_t)grow * DIM + w * 16 + m] = f2b(fmaxf(acc[i], 0.f));
        }
    }
}

// ---------------------------------------------------------------------------
// Fused pool + classifier (batch sorted -> contiguous ranges).
// ---------------------------------------------------------------------------
__global__ __launch_bounds__(384) void pool_classify(
    const unsigned short* __restrict__ h, const int* __restrict__ batch,
    const float* __restrict__ cw1, const float* __restrict__ cb1,
    const float* __restrict__ cw2, const float* __restrict__ cb2,
    float* __restrict__ out)
{
    const int g = blockIdx.x;
    const int t = threadIdx.x;

    int lo = 0, hi = N_NODES;
    while (lo < hi) { int m = (lo + hi) >> 1; if (batch[m] < g) lo = m + 1; else hi = m; }
    const int start = lo;
    hi = N_NODES;
    while (lo < hi) { int m = (lo + hi) >> 1; if (batch[m] < g + 1) lo = m + 1; else hi = m; }
    const int end = lo;

    __shared__ float part[4][DIM];
    __shared__ float gr[DIM];
    __shared__ float hid[DIM];

    const int col = t % DIM;     // 0..95
    const int ty  = t / DIM;     // 0..3

    float s = 0.f;
    for (int n = start + ty; n < end; n += 4)
        s += b2f(h[(size_t)n * DIM + col]);
    part[ty][col] = s;
    __syncthreads();
    if (ty == 0)
        gr[col] = part[0][col] + part[1][col] + part[2][col] + part[3][col];
    __syncthreads();

    float hsum = 0.f;
    const int k0 = ty * (DIM / 4);
#pragma unroll 4
    for (int k = k0; k < k0 + DIM / 4; k++)
        hsum += gr[k] * cw1[k * DIM + col];
    part[ty][col] = hsum;
    __syncthreads();
    if (ty == 0)
        hid[col] = fmaxf(part[0][col] + part[1][col] + part[2][col] + part[3][col]
                         + cb1[col], 0.f);
    __syncthreads();

    if (t < OUT_DIM) {
        float o = cb2[t];
#pragma unroll 4
        for (int k = 0; k < DIM; k++) o += hid[k] * cw2[k * OUT_DIM + t];
        out[g * OUT_DIM + t] = o;
    }
}

// ---------------------------------------------------------------------------
extern "C" void kernel_launch(void* const* d_in, const int* in_sizes, int n_in,
                              void* d_out, int out_size, void* d_ws, size_t ws_size,
                              hipStream_t stream)
{
    const float* x     = (const float*)d_in[0];
    const int*   ei    = (const int*)  d_in[1];
    const int*   batch = (const int*)  d_in[2];
    const float* W1    = (const float*)d_in[3];
    const float* W2    = (const float*)d_in[4];
    const float* cw1   = (const float*)d_in[5];
    const float* cb1   = (const float*)d_in[6];
    const float* cw2   = (const float*)d_in[7];
    const float* cb2   = (const float*)d_in[8];
    float*       out   = (float*)d_out;

    const int* src = ei;             // edge_index[0]
    const int* dst = ei + N_EDGES;   // edge_index[1]

    // workspace layout (16B-aligned at each boundary)
    unsigned short* bufA = (unsigned short*)d_ws;          // [NPAD,96] bf16
    unsigned short* bufB = bufA + (size_t)NPAD * DIM;      // [NPAD,96] bf16
    unsigned short* Bt   = bufB + (size_t)NPAD * DIM;      // [3,96,192] bf16
    int*   cnt    = (int*)(Bt + 3 * DIM * 2 * DIM);        // [NBINS*P1_BLOCKS]
    int*   binned = cnt + NBINS * P1_BLOCKS;               // [NBINS*P1_BLOCKS*SLICECAP]
    int*   csrc   = binned + (size_t)NBINS * P1_BLOCKS * SLICECAP; // [N*CAP]
    int*   deg    = csrc + (size_t)N_NODES * CAP;          // [N]

    prep<<<CAST_NB + CONV_NB, 256, 0, stream>>>(x, W1, W2, bufA, Bt);
    pass1_bin<<<P1_BLOCKS, 256, 0, stream>>>(src, dst, binned, cnt);
    pass2_scatter<<<NBINS, 256, 0, stream>>>(cnt, binned, csrc, deg);

    unsigned short* hin  = bufA;
    unsigned short* hout = bufB;
    for (int l = 0; l < 3; l++) {
        gnn_layer<<<NPAD / 64, 384, 0, stream>>>(hin, deg, csrc,
                                                 Bt + (size_t)l * DIM * 2 * DIM, hout);
        unsigned short* tmp = hin; hin = hout; hout = tmp;
    }

    pool_classify<<<N_GRAPHS, 384, 0, stream>>>(hin, batch, cw1, cb1, cw2, cb2, out);
}

// Round 11
// 253.851 us; speedup vs baseline: 1.4256x; 1.0868x over previous
//
#include <hip/hip_runtime.h>

#define N_NODES   50000
#define N_EDGES   800000
#define DIM       96
#define N_GRAPHS  128
#define OUT_DIM   10
#define NPAD      50048        // 782 * 64 rows (gemm grid coverage)
#define NBINS     391          // coarse bins of 128 nodes
#define P1_BLOCKS 128
#define EPB       (N_EDGES / P1_BLOCKS)   // 6250
#define SLICECAP  48           // per (bin,block) slice capacity: Poisson(16), P(>=48)~1e-10
#define CAP       64           // per-node bucket capacity (Poisson(16) tail ~1e-20)
#define LPAD      104          // LDS agg row stride: 208B = 13x16B (b128-aligned rows)

#define CAST_NB   ((N_NODES * 12 + 255) / 256)        // 2344
#define CONV_NB   ((3 * DIM * 2 * DIM + 255) / 256)   // 216

typedef __attribute__((ext_vector_type(8))) short          short8;
typedef __attribute__((ext_vector_type(8))) unsigned short u16x8;
typedef __attribute__((ext_vector_type(4))) float          f32x4;

__device__ __forceinline__ float b2f(unsigned short u) {
    union { unsigned int i; float f; } v; v.i = ((unsigned int)u) << 16; return v.f;
}
__device__ __forceinline__ unsigned short f2b(float f) {   // round-to-nearest-even
    union { float f; unsigned int i; } v; v.f = f;
    unsigned int u = v.i;
    return (unsigned short)((u + 0x7fffu + ((u >> 16) & 1u)) >> 16);
}

// ---------------------------------------------------------------------------
// Fused {pass1 edge binning | cast x -> bf16 | build Bt}: independent work,
// grid-partitioned (launch-count reduction; fused time ~= max, not sum).
// pass1: zero-global-atomic (rounds 8/9: same-address returning atomics
// ~120ns) — per-block private slices, LDS cursors, plain global writes.
// ---------------------------------------------------------------------------
__global__ __launch_bounds__(256) void prep_pass1(
    const float* __restrict__ x,  const float* __restrict__ W1,
    const float* __restrict__ W2, const int* __restrict__ src,
    const int* __restrict__ dst,  unsigned short* __restrict__ harr,
    unsigned short* __restrict__ Bt, int* __restrict__ binned,
    int* __restrict__ cnt)
{
    __shared__ int cur[NBINS];
    const int b = blockIdx.x;
    const int t = threadIdx.x;

    if (b < P1_BLOCKS) {
        const int e0 = b * EPB;
        for (int i = t; i < NBINS; i += 256) cur[i] = 0;
        __syncthreads();
        for (int e = e0 + t; e < e0 + EPB; e += 256) {
            const int d   = dst[e];
            const int bin = d >> 7;
            const int pos = atomicAdd(&cur[bin], 1);
            if (pos < SLICECAP)
                binned[((size_t)bin * P1_BLOCKS + b) * SLICECAP + pos]
                    = ((d & 127) << 16) | src[e];
        }
        __syncthreads();
        for (int i = t; i < NBINS; i += 256)
            cnt[i * P1_BLOCKS + b] = min(cur[i], SLICECAP);
    } else if (b < P1_BLOCKS + CAST_NB) {
        const int tid = (b - P1_BLOCKS) * 256 + t;    // one per 8 cols
        if (tid >= N_NODES * 12) return;
        const int node = tid / 12;
        const int c    = (tid - node * 12) * 8;
        const float4 v0 = *(const float4*)(x + (size_t)node * DIM + c);
        const float4 v1 = *(const float4*)(x + (size_t)node * DIM + c + 4);
        u16x8 o;
        o[0] = f2b(v0.x); o[1] = f2b(v0.y); o[2] = f2b(v0.z); o[3] = f2b(v0.w);
        o[4] = f2b(v1.x); o[5] = f2b(v1.y); o[6] = f2b(v1.z); o[7] = f2b(v1.w);
        *(u16x8*)(harr + (size_t)node * DIM + c) = o;
    } else {
        const int idx = (b - P1_BLOCKS - CAST_NB) * 256 + t;  // Bt[l][n][k]
        if (idx >= 3 * DIM * 2 * DIM) return;
        const int l   = idx / (DIM * 2 * DIM);
        const int rem = idx - l * (DIM * 2 * DIM);
        const int n   = rem / (2 * DIM);
        const int k   = rem - n * (2 * DIM);
        const float v = (k < DIM) ? W1[(size_t)l * DIM * DIM + k * DIM + n]
                                  : W2[(size_t)l * DIM * DIM + (k - DIM) * DIM + n];
        Bt[idx] = f2b(v);
    }
}

// ---------------------------------------------------------------------------
// Pass 2: one block per bin (128 nodes).  Two threads walk each slice
// directly (parity split) — no scan, no per-edge binary search; LDS per-node
// cursors claim csrc slots (bucket fill order is irrelevant).  No global atomics.
// ---------------------------------------------------------------------------
__global__ __launch_bounds__(256) void pass2_scatter(const int* __restrict__ cnt,
                                                     const int* __restrict__ binned,
                                                     int* __restrict__ csrc,
                                                     int* __restrict__ deg)
{
    __shared__ int ncnt[128];
    const int bin = blockIdx.x;
    const int t   = threadIdx.x;
    const int n0  = bin << 7;

    if (t < 128) ncnt[t] = 0;
    __syncthreads();

    const int slice = t >> 1;        // 0..127
    const int par   = t & 1;
    const int c     = cnt[bin * P1_BLOCKS + slice];
    const int* __restrict__ bb = binned + ((size_t)bin * P1_BLOCKS + slice) * SLICECAP;

    for (int i = par; i < c; i += 2) {
        const int v    = bb[i];
        const int dlow = v >> 16;
        const int s    = v & 0xffff;                  // src fits 16 bits (N<65536)
        const int pos  = atomicAdd(&ncnt[dlow], 1);   // LDS atomic
        if (pos < CAP) csrc[(size_t)(n0 + dlow) * CAP + pos] = s;
    }
    __syncthreads();

    if (t < 128 && n0 + t < N_NODES) deg[n0 + t] = min(ncnt[t], CAP);
}

// ---------------------------------------------------------------------------
// Fused layer.  Phase 1: single-bucket gather (rounds 8/9 falsified divergence
// and L2-partition theories; ~45us is this access shape's line-request rate).
// Phase 2: mfma_f32_16x16x32_bf16, A-frag A[m=lane&15][k=quad*8+j], C/D
// col=lane&15,row=quad*4+reg (m89-verified); bfrag hoisted above the gather.
// Epilogue: acc -> LDS tile -> coalesced u16x8 stores (replaces 16x2B
// scattered global stores/thread with 2x16B).
// ---------------------------------------------------------------------------
__global__ __launch_bounds__(384) void gnn_layer(
    const unsigned short* __restrict__ harr, const int* __restrict__ deg,
    const int* __restrict__ csrc, const unsigned short* __restrict__ Btl,
    unsigned short* __restrict__ hout)
{
    __shared__ unsigned short aggLds[64][LPAD];
    const int t       = threadIdx.x;
    const int rowBase = blockIdx.x * 64;

    // hoisted B fragments (overlap with gather)
    const int lane = t & 63;
    const int w    = t >> 6;    // 0..5 col tile
    const int m    = lane & 15;
    const int q    = lane >> 4;
    short8 bfrag[6];
#pragma unroll
    for (int s = 0; s < 6; s++)
        bfrag[s] = *(const short8*)(Btl + (size_t)(w * 16 + m) * (2 * DIM) + s * 32 + q * 8);

    // ---- phase 1: gather ----
    {
        const int r    = t / 6;          // 0..63
        const int sub  = t - r * 6;      // 0..5
        const int node = rowBase + r;
        const int off  = sub * 16;       // 16 bf16 = 32B per thread

        float a[16];
#pragma unroll
        for (int i = 0; i < 16; i++) a[i] = 0.f;

        if (node < N_NODES) {
            const int d = deg[node];
            const int* __restrict__ bkt = csrc + (size_t)node * CAP;
            const unsigned short* __restrict__ hb = harr + off;

            const int nfull = d & ~3;
            int c = 0;
            for (; c < nfull; c += 4) {
                const int4 s = *(const int4*)(bkt + c);
                const unsigned short* p0 = hb + (size_t)s.x * DIM;
                const unsigned short* p1 = hb + (size_t)s.y * DIM;
                const unsigned short* p2 = hb + (size_t)s.z * DIM;
                const unsigned short* p3 = hb + (size_t)s.w * DIM;
                const u16x8 va0 = *(const u16x8*)(p0), vb0 = *(const u16x8*)(p0 + 8);
                const u16x8 va1 = *(const u16x8*)(p1), vb1 = *(const u16x8*)(p1 + 8);
                const u16x8 va2 = *(const u16x8*)(p2), vb2 = *(const u16x8*)(p2 + 8);
                const u16x8 va3 = *(const u16x8*)(p3), vb3 = *(const u16x8*)(p3 + 8);
#pragma unroll
                for (int i = 0; i < 8; i++) {
                    a[i]     += b2f(va0[i]) + b2f(va1[i]) + b2f(va2[i]) + b2f(va3[i]);
                    a[i + 8] += b2f(vb0[i]) + b2f(vb1[i]) + b2f(vb2[i]) + b2f(vb3[i]);
                }
            }
            for (; c < d; c++) {
                const unsigned short* p0 = hb + (size_t)bkt[c] * DIM;
                const u16x8 va0 = *(const u16x8*)(p0), vb0 = *(const u16x8*)(p0 + 8);
#pragma unroll
                for (int i = 0; i < 8; i++) {
                    a[i]     += b2f(va0[i]);
                    a[i + 8] += b2f(vb0[i]);
                }
            }
        }

        u16x8 o0, o1;
#pragma unroll
        for (int i = 0; i < 8; i++) { o0[i] = f2b(a[i]); o1[i] = f2b(a[i + 8]); }
        *(u16x8*)(&aggLds[r][off])     = o0;
        *(u16x8*)(&aggLds[r][off + 8]) = o1;
    }
    __syncthreads();

    // ---- phase 2: MFMA (all accs first; aggLds still holds the agg tile) ----
    f32x4 accv[4];
#pragma unroll
    for (int r = 0; r < 4; r++) {
        const int rb = rowBase + r * 16;
        f32x4 acc = {0.f, 0.f, 0.f, 0.f};
        const unsigned short* ah = harr + (size_t)(rb + m) * DIM + q * 8;
#pragma unroll
        for (int s = 0; s < 3; s++) {
            const short8 af = *(const short8*)(ah + s * 32);
            acc = __builtin_amdgcn_mfma_f32_16x16x32_bf16(af, bfrag[s], acc, 0, 0, 0);
        }
#pragma unroll
        for (int s = 0; s < 3; s++) {
            const short8 af = *(const short8*)(&aggLds[r * 16 + m][s * 32 + q * 8]);
            acc = __builtin_amdgcn_mfma_f32_16x16x32_bf16(af, bfrag[s + 3], acc, 0, 0, 0);
        }
        accv[r] = acc;
    }
    __syncthreads();            // all aggLds reads done; safe to overwrite

    // ---- epilogue: acc -> LDS -> coalesced stores ----
#pragma unroll
    for (int r = 0; r < 4; r++)
#pragma unroll
        for (int i = 0; i < 4; i++)
            aggLds[r * 16 + q * 4 + i][w * 16 + m] = f2b(fmaxf(accv[r][i], 0.f));
    __syncthreads();

#pragma unroll
    for (int k = 0; k < 2; k++) {
        const int idx = t + k * 384;     // 768 chunks: 64 rows x 12 x 16B
        const int row = idx / 12;
        const int ch  = idx - row * 12;
        const int grow = rowBase + row;
        if (grow < N_NODES)
            *(u16x8*)(hout + (size_t)grow * DIM + ch * 8)
                = *(const u16x8*)(&aggLds[row][ch * 8]);
    }
}

// ---------------------------------------------------------------------------
// Fused pool + classifier, 960 threads (10-way row split for the pooling walk).
// ---------------------------------------------------------------------------
__global__ __launch_bounds__(960) void pool_classify(
    const unsigned short* __restrict__ h, const int* __restrict__ batch,
    const float* __restrict__ cw1, const float* __restrict__ cb1,
    const float* __restrict__ cw2, const float* __restrict__ cb2,
    float* __restrict__ out)
{
    const int g = blockIdx.x;
    const int t = threadIdx.x;

    int lo = 0, hi = N_NODES;
    while (lo < hi) { int m = (lo + hi) >> 1; if (batch[m] < g) lo = m + 1; else hi = m; }
    const int start = lo;
    hi = N_NODES;
    while (lo < hi) { int m = (lo + hi) >> 1; if (batch[m] < g + 1) lo = m + 1; else hi = m; }
    const int end = lo;

    __shared__ float part[10][DIM];
    __shared__ float gr[DIM];
    __shared__ float hid[DIM];

    const int col = t % DIM;     // 0..95
    const int ty  = t / DIM;     // 0..9

    float s = 0.f;
    for (int n = start + ty; n < end; n += 10)
        s += b2f(h[(size_t)n * DIM + col]);
    part[ty][col] = s;
    __syncthreads();
    if (ty == 0) {
        float acc = 0.f;
#pragma unroll
        for (int p = 0; p < 10; p++) acc += part[p][col];
        gr[col] = acc;
    }
    __syncthreads();

    if (ty < 4) {                // hidden = relu(gr @ cw1 + cb1), k split 4-way
        float hsum = 0.f;
        const int k0 = ty * (DIM / 4);
#pragma unroll 4
        for (int k = k0; k < k0 + DIM / 4; k++)
            hsum += gr[k] * cw1[k * DIM + col];
        part[ty][col] = hsum;
    }
    __syncthreads();
    if (ty == 0)
        hid[col] = fmaxf(part[0][col] + part[1][col] + part[2][col] + part[3][col]
                         + cb1[col], 0.f);
    __syncthreads();

    if (t < OUT_DIM) {
        float o = cb2[t];
#pragma unroll 4
        for (int k = 0; k < DIM; k++) o += hid[k] * cw2[k * OUT_DIM + t];
        out[g * OUT_DIM + t] = o;
    }
}

// ---------------------------------------------------------------------------
extern "C" void kernel_launch(void* const* d_in, const int* in_sizes, int n_in,
                              void* d_out, int out_size, void* d_ws, size_t ws_size,
                              hipStream_t stream)
{
    const float* x     = (const float*)d_in[0];
    const int*   ei    = (const int*)  d_in[1];
    const int*   batch = (const int*)  d_in[2];
    const float* W1    = (const float*)d_in[3];
    const float* W2    = (const float*)d_in[4];
    const float* cw1   = (const float*)d_in[5];
    const float* cb1   = (const float*)d_in[6];
    const float* cw2   = (const float*)d_in[7];
    const float* cb2   = (const float*)d_in[8];
    float*       out   = (float*)d_out;

    const int* src = ei;             // edge_index[0]
    const int* dst = ei + N_EDGES;   // edge_index[1]

    // workspace layout (16B-aligned at each boundary)
    unsigned short* bufA = (unsigned short*)d_ws;          // [NPAD,96] bf16
    unsigned short* bufB = bufA + (size_t)NPAD * DIM;      // [NPAD,96] bf16
    unsigned short* Bt   = bufB + (size_t)NPAD * DIM;      // [3,96,192] bf16
    int*   cnt    = (int*)(Bt + 3 * DIM * 2 * DIM);        // [NBINS*P1_BLOCKS]
    int*   binned = cnt + NBINS * P1_BLOCKS;               // [NBINS*P1_BLOCKS*SLICECAP]
    int*   csrc   = binned + (size_t)NBINS * P1_BLOCKS * SLICECAP; // [N*CAP]
    int*   deg    = csrc + (size_t)N_NODES * CAP;          // [N]

    prep_pass1<<<P1_BLOCKS + CAST_NB + CONV_NB, 256, 0, stream>>>(
        x, W1, W2, src, dst, bufA, Bt, binned, cnt);
    pass2_scatter<<<NBINS, 256, 0, stream>>>(cnt, binned, csrc, deg);

    unsigned short* hin  = bufA;
    unsigned short* hout = bufB;
    for (int l = 0; l < 3; l++) {
        gnn_layer<<<NPAD / 64, 384, 0, stream>>>(hin, deg, csrc,
                                                 Bt + (size_t)l * DIM * 2 * DIM, hout);
        unsigned short* tmp = hin; hin = hout; hout = tmp;
    }

    pool_classify<<<N_GRAPHS, 960, 0, stream>>>(hin, batch, cw1, cb1, cw2, cb2, out);
}